// Round 6
// baseline (2845.660 us; speedup 1.0000x reference)
//
#include <hip/hip_runtime.h>

#define D 128
#define NLAYERS 5
#define SCAN_TILE 1024
#define ZSTRIDE 132   // fp32 zacc row stride (pad: spreads LDS-atomic banks, keeps 16B align)

using short8  = __attribute__((ext_vector_type(8))) short;
using short4v = __attribute__((ext_vector_type(4))) short;
using floatx4 = __attribute__((ext_vector_type(4))) float;

__device__ __forceinline__ unsigned bf16_rne(float x) {
    unsigned u = __float_as_uint(x);
    return (u + 0x7fffu + ((u >> 16) & 1u)) >> 16;
}
__device__ __forceinline__ float bf16_to_f32(short s) {
    return __uint_as_float(((unsigned)(unsigned short)s) << 16);
}

// ---------------- gather: H = bf16(emb[x]) ----------------
__global__ void gather_kernel(const int* __restrict__ x, const float* __restrict__ emb,
                              short* __restrict__ h, int n_nodes) {
    int tid = blockIdx.x * 256 + threadIdx.x;
    int node = tid >> 5;
    if (node >= n_nodes) return;
    int lane = tid & 31;
    int s = x[node];
    const float4 v = *reinterpret_cast<const float4*>(emb + (size_t)s * D + lane * 4);
    short4v o;
    o[0] = (short)bf16_rne(v.x); o[1] = (short)bf16_rne(v.y);
    o[2] = (short)bf16_rne(v.z); o[3] = (short)bf16_rne(v.w);
    *reinterpret_cast<short4v*>(h + (size_t)node * D + lane * 4) = o;
}

// ---------------- CSR build ----------------
__global__ void zero_int_kernel(int* __restrict__ p, int n) {
    int i = blockIdx.x * 256 + threadIdx.x;
    if (i < n) p[i] = 0;
}

__global__ void hist_kernel(const int* __restrict__ edst, int* __restrict__ deg, int n_edges) {
    int e = blockIdx.x * 256 + threadIdx.x;
    if (e < n_edges) atomicAdd(&deg[edst[e]], 1);
}

__global__ void scan_sums_kernel(const int* __restrict__ deg, int* __restrict__ bsums, int n) {
    __shared__ int red[256];
    int base = blockIdx.x * SCAN_TILE + threadIdx.x * 4;
    int s = 0;
    #pragma unroll
    for (int j = 0; j < 4; j++) {
        int i = base + j;
        if (i < n) s += deg[i];
    }
    red[threadIdx.x] = s;
    __syncthreads();
    for (int off = 128; off > 0; off >>= 1) {
        if (threadIdx.x < off) red[threadIdx.x] += red[threadIdx.x + off];
        __syncthreads();
    }
    if (threadIdx.x == 0) bsums[blockIdx.x] = red[0];
}

__global__ void scan_bsums_kernel(int* __restrict__ bsums, int nblocks) {
    __shared__ int sdata[256];
    int carry = 0;
    for (int base = 0; base < nblocks; base += 256) {
        int i = base + threadIdx.x;
        int v = (i < nblocks) ? bsums[i] : 0;
        sdata[threadIdx.x] = v;
        __syncthreads();
        for (int off = 1; off < 256; off <<= 1) {
            int t = (threadIdx.x >= off) ? sdata[threadIdx.x - off] : 0;
            __syncthreads();
            sdata[threadIdx.x] += t;
            __syncthreads();
        }
        int incl = sdata[threadIdx.x];
        if (i < nblocks) bsums[i] = carry + incl - v;
        carry += sdata[255];
        __syncthreads();
    }
}

__global__ void scan_final_kernel(const int* __restrict__ deg, const int* __restrict__ bsums,
                                  int* __restrict__ offsets, int* __restrict__ cursor, int n) {
    __shared__ int sdata[256];
    int base = blockIdx.x * SCAN_TILE + threadIdx.x * 4;
    int v[4];
    int s = 0;
    #pragma unroll
    for (int j = 0; j < 4; j++) {
        int i = base + j;
        v[j] = (i < n) ? deg[i] : 0;
        s += v[j];
    }
    sdata[threadIdx.x] = s;
    __syncthreads();
    for (int off = 1; off < 256; off <<= 1) {
        int t = (threadIdx.x >= off) ? sdata[threadIdx.x - off] : 0;
        __syncthreads();
        sdata[threadIdx.x] += t;
        __syncthreads();
    }
    int excl = sdata[threadIdx.x] - s + bsums[blockIdx.x];
    #pragma unroll
    for (int j = 0; j < 4; j++) {
        int i = base + j;
        if (i <= n) offsets[i] = excl;
        if (i < n) cursor[i] = excl;
        excl += v[j];
    }
}

__global__ void fill_kernel(const int* __restrict__ esrc, const int* __restrict__ edst,
                            int* __restrict__ cursor, int2* __restrict__ csr_ed, int n_edges) {
    int e = blockIdx.x * 256 + threadIdx.x;
    if (e >= n_edges) return;
    int s = esrc[e], d = edst[e];
    int pos = atomicAdd(&cursor[d], 1);
    csr_ed[pos] = make_int2(s, d);
}

// ---------------- W prep: wt[mat][n][k] = bf16(W[mat][k][n]) ----------------
__global__ void wsplit_kernel(const float* __restrict__ Wa, const float* __restrict__ Wb,
                              short* __restrict__ wt) {
    int mat = blockIdx.y;
    const float* W = (mat & 1) ? (Wb + (size_t)(mat >> 1) * D * D)
                               : (Wa + (size_t)(mat >> 1) * D * D);
    int idx = blockIdx.x * 256 + threadIdx.x;
    int n = idx >> 7, k = idx & 127;
    wt[(size_t)mat * D * D + idx] = (short)bf16_rne(W[k * D + n]);
}

// ---------------- fused layer: H_out = relu(relu((H+agg) @ Wa + ba) @ Wb + bb) ----------------
// block: 128 nodes, 1024 threads (16 waves). Edge-parallel aggregation into fp32 LDS
// (ds_add_f32, no serial per-node chain), then 2 MFMA GEMMs.
// LDS: zacc 128x132 f32 (67.6KB, bf16 z/t tile aliases its head) + wa 32KB + wb 32KB = 132KB
// -> 1 block/CU, 16 waves. 16B chunks XOR-swizzled in bf16 tiles -> 0 conflicts (R3-R5).
__global__ __launch_bounds__(1024, 4) void layer_kernel(
        const int* __restrict__ offsets, const int2* __restrict__ csr_ed,
        const short* __restrict__ h_in, const short* __restrict__ wta,
        const short* __restrict__ wtb, const float* __restrict__ ba,
        const float* __restrict__ bb, short* __restrict__ h_out, int n_rows) {
    __shared__ __align__(16) float zacc[128 * ZSTRIDE];   // fp32 accumulator
    __shared__ __align__(16) short wa[128 * 128];
    __shared__ __align__(16) short wb[128 * 128];
    short* zt = (short*)zacc;                             // bf16 z/t tile (32KB, aliases head)

    const int tid  = threadIdx.x;
    const int row0 = blockIdx.x * 128;

    // stage Wa/Wb ([n][k] bf16): 2048 chunks each
    #pragma unroll
    for (int i = 0; i < 2; i++) {
        int g = i * 1024 + tid;
        int n = g >> 4, c = g & 15;
        int off = (n * 16 + (c ^ (n & 15))) * 8;
        *reinterpret_cast<short8*>(&wa[off]) =
            *reinterpret_cast<const short8*>(wta + n * D + c * 8);
        *reinterpret_cast<short8*>(&wb[off]) =
            *reinterpret_cast<const short8*>(wtb + n * D + c * 8);
    }

    // init zacc with self term: z[r] = f32(h_in[row0+r])
    #pragma unroll
    for (int i = 0; i < 2; i++) {
        int g = i * 1024 + tid;
        int r = g >> 4, c = g & 15;
        int gr = row0 + r;
        float f[8];
        if (gr < n_rows) {
            short8 sv = *reinterpret_cast<const short8*>(h_in + (size_t)gr * D + c * 8);
            #pragma unroll
            for (int j = 0; j < 8; j++) f[j] = bf16_to_f32(sv[j]);
        } else {
            #pragma unroll
            for (int j = 0; j < 8; j++) f[j] = 0.f;
        }
        float* zp = &zacc[r * ZSTRIDE + c * 8];
        *reinterpret_cast<float4*>(zp)     = make_float4(f[0], f[1], f[2], f[3]);
        *reinterpret_cast<float4*>(zp + 4) = make_float4(f[4], f[5], f[6], f[7]);
    }
    __syncthreads();

    // edge-parallel aggregation: group g (64 groups x 16 lanes) streams edges beg+g, beg+g+64, ...
    {
        const int group = tid >> 4;
        const int l16   = tid & 15;
        const int row_hi = (row0 + 128 < n_rows) ? (row0 + 128) : n_rows;
        const int beg = offsets[row0];
        const int end = offsets[row_hi];
        int p = beg + group;
        for (; p + 64 < end; p += 128) {
            int2 e0 = csr_ed[p];
            int2 e1 = csr_ed[p + 64];
            short8 v0 = *reinterpret_cast<const short8*>(h_in + (size_t)e0.x * D + l16 * 8);
            short8 v1 = *reinterpret_cast<const short8*>(h_in + (size_t)e1.x * D + l16 * 8);
            float* z0 = &zacc[(e0.y - row0) * ZSTRIDE + l16 * 8];
            float* z1 = &zacc[(e1.y - row0) * ZSTRIDE + l16 * 8];
            #pragma unroll
            for (int j = 0; j < 8; j++) atomicAdd(&z0[j], bf16_to_f32(v0[j]));
            #pragma unroll
            for (int j = 0; j < 8; j++) atomicAdd(&z1[j], bf16_to_f32(v1[j]));
        }
        if (p < end) {
            int2 e0 = csr_ed[p];
            short8 v0 = *reinterpret_cast<const short8*>(h_in + (size_t)e0.x * D + l16 * 8);
            float* z0 = &zacc[(e0.y - row0) * ZSTRIDE + l16 * 8];
            #pragma unroll
            for (int j = 0; j < 8; j++) atomicAdd(&z0[j], bf16_to_f32(v0[j]));
        }
    }
    __syncthreads();

    // convert zacc fp32 -> swizzled bf16 tile (in place; zt aliases zacc head)
    {
        int q0 = tid * 2;
        float4 a0, a1, b0, b1;
        int r0q = q0 >> 4, c0q = q0 & 15;
        int r1q = (q0 + 1) >> 4, c1q = (q0 + 1) & 15;
        a0 = *reinterpret_cast<const float4*>(&zacc[r0q * ZSTRIDE + c0q * 8]);
        a1 = *reinterpret_cast<const float4*>(&zacc[r0q * ZSTRIDE + c0q * 8 + 4]);
        b0 = *reinterpret_cast<const float4*>(&zacc[r1q * ZSTRIDE + c1q * 8]);
        b1 = *reinterpret_cast<const float4*>(&zacc[r1q * ZSTRIDE + c1q * 8 + 4]);
        __syncthreads();
        short8 o0, o1;
        o0[0]=(short)bf16_rne(a0.x); o0[1]=(short)bf16_rne(a0.y); o0[2]=(short)bf16_rne(a0.z); o0[3]=(short)bf16_rne(a0.w);
        o0[4]=(short)bf16_rne(a1.x); o0[5]=(short)bf16_rne(a1.y); o0[6]=(short)bf16_rne(a1.z); o0[7]=(short)bf16_rne(a1.w);
        o1[0]=(short)bf16_rne(b0.x); o1[1]=(short)bf16_rne(b0.y); o1[2]=(short)bf16_rne(b0.z); o1[3]=(short)bf16_rne(b0.w);
        o1[4]=(short)bf16_rne(b1.x); o1[5]=(short)bf16_rne(b1.y); o1[6]=(short)bf16_rne(b1.z); o1[7]=(short)bf16_rne(b1.w);
        *reinterpret_cast<short8*>(&zt[(r0q * 16 + (c0q ^ (r0q & 15))) * 8]) = o0;
        *reinterpret_cast<short8*>(&zt[(r1q * 16 + (c1q ^ (r1q & 15))) * 8]) = o1;
    }
    __syncthreads();

    const int lane = tid & 63;
    const int wave = tid >> 6;
    const int wr   = wave >> 1;     // 16-row group (0..7)
    const int wc   = wave & 1;      // 64-col group
    const int lm   = lane & 15;
    const int quad = lane >> 4;

    // ---- GEMM1: t = relu(z @ Wa + ba) ----
    floatx4 acc1[4];
    #pragma unroll
    for (int b = 0; b < 4; b++) acc1[b] = floatx4{0.f, 0.f, 0.f, 0.f};
    {
        const int r = wr * 16 + lm;
        #pragma unroll
        for (int ks = 0; ks < 4; ks++) {
            const int c = ks * 4 + quad;
            short8 av = *reinterpret_cast<const short8*>(&zt[(r * 16 + (c ^ (r & 15))) * 8]);
            #pragma unroll
            for (int cs = 0; cs < 4; cs++) {
                int nn = wc * 64 + cs * 16 + lm;
                short8 bv = *reinterpret_cast<const short8*>(&wa[(nn * 16 + (c ^ (nn & 15))) * 8]);
                acc1[cs] = __builtin_amdgcn_mfma_f32_16x16x32_bf16(av, bv, acc1[cs], 0, 0, 0);
            }
        }
    }
    __syncthreads();   // all zt reads complete before t overwrites

    // epilogue1: bias + relu + bf16, t -> zt (C layout: row=quad*4+reg, col=lm)
    #pragma unroll
    for (int cs = 0; cs < 4; cs++) {
        int col = wc * 64 + cs * 16 + lm;
        float bva = ba[col];
        int cj = col >> 3, ci = col & 7;
        #pragma unroll
        for (int reg = 0; reg < 4; reg++) {
            int r = wr * 16 + quad * 4 + reg;
            float v = fmaxf(acc1[cs][reg] + bva, 0.f);
            zt[(r * 16 + (cj ^ (r & 15))) * 8 + ci] = (short)bf16_rne(v);
        }
    }
    __syncthreads();

    // ---- GEMM2: h = relu(t @ Wb + bb) ----
    floatx4 acc2[4];
    #pragma unroll
    for (int b = 0; b < 4; b++) acc2[b] = floatx4{0.f, 0.f, 0.f, 0.f};
    {
        const int r = wr * 16 + lm;
        #pragma unroll
        for (int ks = 0; ks < 4; ks++) {
            const int c = ks * 4 + quad;
            short8 av = *reinterpret_cast<const short8*>(&zt[(r * 16 + (c ^ (r & 15))) * 8]);
            #pragma unroll
            for (int cs = 0; cs < 4; cs++) {
                int nn = wc * 64 + cs * 16 + lm;
                short8 bv = *reinterpret_cast<const short8*>(&wb[(nn * 16 + (c ^ (nn & 15))) * 8]);
                acc2[cs] = __builtin_amdgcn_mfma_f32_16x16x32_bf16(av, bv, acc2[cs], 0, 0, 0);
            }
        }
    }

    // epilogue2: bias + relu + bf16 -> global
    #pragma unroll
    for (int cs = 0; cs < 4; cs++) {
        int col = wc * 64 + cs * 16 + lm;
        float bvb = bb[col];
        #pragma unroll
        for (int reg = 0; reg < 4; reg++) {
            int r = row0 + wr * 16 + quad * 4 + reg;
            if (r < n_rows) {
                float v = fmaxf(acc2[cs][reg] + bvb, 0.f);
                h_out[(size_t)r * D + col] = (short)bf16_rne(v);
            }
        }
    }
}

// ---------------- pooling: pooled[c] = sum_r f32(H[r][c]) ----------------
__global__ void zero_kernel(float* __restrict__ p) { p[threadIdx.x] = 0.f; }

__global__ void pool_kernel(const short* __restrict__ h, float* __restrict__ pooled, int n_rows) {
    const int c8 = threadIdx.x & 15;
    const int rg = threadIdx.x >> 4;
    const int r0 = blockIdx.x * 256;
    const int rend = min(r0 + 256, n_rows);
    float acc[8];
    #pragma unroll
    for (int j = 0; j < 8; j++) acc[j] = 0.f;
    for (int r = r0 + rg; r < rend; r += 16) {
        short8 v = *reinterpret_cast<const short8*>(h + (size_t)r * D + c8 * 8);
        #pragma unroll
        for (int j = 0; j < 8; j++) acc[j] += bf16_to_f32(v[j]);
    }
    __shared__ float red[16][128];
    #pragma unroll
    for (int j = 0; j < 8; j++) red[rg][c8 * 8 + j] = acc[j];
    __syncthreads();
    if (threadIdx.x < 128) {
        float s = 0.f;
        #pragma unroll
        for (int g = 0; g < 16; g++) s += red[g][threadIdx.x];
        atomicAdd(&pooled[threadIdx.x], s);
    }
}

// ---------------- final linear (fp32 exact) ----------------
__global__ void final_kernel(const float* __restrict__ pooled, const float* __restrict__ Wlin,
                             const float* __restrict__ blin, float* __restrict__ out) {
    const int j = threadIdx.x;
    __shared__ float p[D];
    p[j] = pooled[j];
    __syncthreads();
    float s = blin[j];
    #pragma unroll 8
    for (int k = 0; k < D; k++) s += p[k] * Wlin[k * D + j];
    out[j] = s;
}

extern "C" void kernel_launch(void* const* d_in, const int* in_sizes, int n_in,
                              void* d_out, int out_size, void* d_ws, size_t ws_size,
                              hipStream_t stream) {
    const int*   x    = (const int*)d_in[0];
    const int*   ei   = (const int*)d_in[1];
    const float* emb  = (const float*)d_in[2];
    const float* Wa   = (const float*)d_in[3];
    const float* ba   = (const float*)d_in[4];
    const float* Wb   = (const float*)d_in[5];
    const float* bb   = (const float*)d_in[6];
    const float* Wlin = (const float*)d_in[7];
    const float* blin = (const float*)d_in[8];
    float* out = (float*)d_out;

    const int N = in_sizes[0];
    const int E = in_sizes[1] / 2;
    const int* esrc = ei;
    const int* edst = ei + E;

    // workspace layout: H (bf16, double-buffered) | pooled | CSR | wt
    short* H0 = (short*)d_ws;                       // N*D
    short* H1 = H0 + (size_t)N * D;                 // N*D
    float* pooled = (float*)(H1 + (size_t)N * D);   // 128
    int* deg     = (int*)(pooled + 128);            // N
    int* offsets = deg + N;                         // N+1
    int* cursor  = offsets + (N + 1);               // N
    int* bsums   = cursor + N;                      // 4096
    uintptr_t ed_addr = ((uintptr_t)(bsums + 4096) + 15) & ~(uintptr_t)15;
    int2* csr_ed = (int2*)ed_addr;                  // E int2
    uintptr_t wt_addr = ((uintptr_t)(csr_ed + E) + 15) & ~(uintptr_t)15;
    short* wt = (short*)wt_addr;                    // [10][128][128] bf16

    const int scan_blocks = (N + 1 + SCAN_TILE - 1) / SCAN_TILE;

    wsplit_kernel<<<dim3(64, 2 * NLAYERS), 256, 0, stream>>>(Wa, Wb, wt);

    zero_int_kernel<<<(N + 255) / 256, 256, 0, stream>>>(deg, N);
    hist_kernel<<<(E + 255) / 256, 256, 0, stream>>>(edst, deg, E);
    scan_sums_kernel<<<scan_blocks, 256, 0, stream>>>(deg, bsums, N);
    scan_bsums_kernel<<<1, 256, 0, stream>>>(bsums, scan_blocks);
    scan_final_kernel<<<scan_blocks, 256, 0, stream>>>(deg, bsums, offsets, cursor, N);
    fill_kernel<<<(E + 255) / 256, 256, 0, stream>>>(esrc, edst, cursor, csr_ed, E);

    gather_kernel<<<(N * 32 + 255) / 256, 256, 0, stream>>>(x, emb, H0, N);

    const int layer_blocks = (N + 127) / 128;
    short* hin = H0; short* hout = H1;
    for (int l = 0; l < NLAYERS; l++) {
        layer_kernel<<<layer_blocks, 1024, 0, stream>>>(
            offsets, csr_ed, hin,
            wt + (size_t)(2 * l) * D * D, wt + (size_t)(2 * l + 1) * D * D,
            ba + (size_t)l * D, bb + (size_t)l * D, hout, N);
        short* tmp = hin; hin = hout; hout = tmp;
    }

    zero_kernel<<<1, 128, 0, stream>>>(pooled);
    pool_kernel<<<(N + 255) / 256, 256, 0, stream>>>(hin, pooled, N);
    final_kernel<<<1, 128, 0, stream>>>(pooled, Wlin, blin, out);
}

// Round 7
// 459.607 us; speedup vs baseline: 6.1915x; 6.1915x over previous
//
#include <hip/hip_runtime.h>

#define D 128
#define NLAYERS 5
#define SCAN_TILE 1024

using short8  = __attribute__((ext_vector_type(8))) short;
using short4v = __attribute__((ext_vector_type(4))) short;
using floatx4 = __attribute__((ext_vector_type(4))) float;

__device__ __forceinline__ unsigned bf16_rne(float x) {
    unsigned u = __float_as_uint(x);
    return (u + 0x7fffu + ((u >> 16) & 1u)) >> 16;
}
__device__ __forceinline__ float bf16_to_f32(short s) {
    return __uint_as_float(((unsigned)(unsigned short)s) << 16);
}

// ---------------- gather: H = bf16(emb[x]) ----------------
__global__ void gather_kernel(const int* __restrict__ x, const float* __restrict__ emb,
                              short* __restrict__ h, int n_nodes) {
    int tid = blockIdx.x * 256 + threadIdx.x;
    int node = tid >> 5;
    if (node >= n_nodes) return;
    int lane = tid & 31;
    int s = x[node];
    const float4 v = *reinterpret_cast<const float4*>(emb + (size_t)s * D + lane * 4);
    short4v o;
    o[0] = (short)bf16_rne(v.x); o[1] = (short)bf16_rne(v.y);
    o[2] = (short)bf16_rne(v.z); o[3] = (short)bf16_rne(v.w);
    *reinterpret_cast<short4v*>(h + (size_t)node * D + lane * 4) = o;
}

// ---------------- CSR build ----------------
__global__ void zero_int_kernel(int* __restrict__ p, int n) {
    int i = blockIdx.x * 256 + threadIdx.x;
    if (i < n) p[i] = 0;
}

__global__ void hist_kernel(const int* __restrict__ edst, int* __restrict__ deg, int n_edges) {
    int e = blockIdx.x * 256 + threadIdx.x;
    if (e < n_edges) atomicAdd(&deg[edst[e]], 1);
}

__global__ void scan_sums_kernel(const int* __restrict__ deg, int* __restrict__ bsums, int n) {
    __shared__ int red[256];
    int base = blockIdx.x * SCAN_TILE + threadIdx.x * 4;
    int s = 0;
    #pragma unroll
    for (int j = 0; j < 4; j++) {
        int i = base + j;
        if (i < n) s += deg[i];
    }
    red[threadIdx.x] = s;
    __syncthreads();
    for (int off = 128; off > 0; off >>= 1) {
        if (threadIdx.x < off) red[threadIdx.x] += red[threadIdx.x + off];
        __syncthreads();
    }
    if (threadIdx.x == 0) bsums[blockIdx.x] = red[0];
}

__global__ void scan_bsums_kernel(int* __restrict__ bsums, int nblocks) {
    __shared__ int sdata[256];
    int carry = 0;
    for (int base = 0; base < nblocks; base += 256) {
        int i = base + threadIdx.x;
        int v = (i < nblocks) ? bsums[i] : 0;
        sdata[threadIdx.x] = v;
        __syncthreads();
        for (int off = 1; off < 256; off <<= 1) {
            int t = (threadIdx.x >= off) ? sdata[threadIdx.x - off] : 0;
            __syncthreads();
            sdata[threadIdx.x] += t;
            __syncthreads();
        }
        int incl = sdata[threadIdx.x];
        if (i < nblocks) bsums[i] = carry + incl - v;
        carry += sdata[255];
        __syncthreads();
    }
}

__global__ void scan_final_kernel(const int* __restrict__ deg, const int* __restrict__ bsums,
                                  int* __restrict__ offsets, int* __restrict__ cursor, int n) {
    __shared__ int sdata[256];
    int base = blockIdx.x * SCAN_TILE + threadIdx.x * 4;
    int v[4];
    int s = 0;
    #pragma unroll
    for (int j = 0; j < 4; j++) {
        int i = base + j;
        v[j] = (i < n) ? deg[i] : 0;
        s += v[j];
    }
    sdata[threadIdx.x] = s;
    __syncthreads();
    for (int off = 1; off < 256; off <<= 1) {
        int t = (threadIdx.x >= off) ? sdata[threadIdx.x - off] : 0;
        __syncthreads();
        sdata[threadIdx.x] += t;
        __syncthreads();
    }
    int excl = sdata[threadIdx.x] - s + bsums[blockIdx.x];
    #pragma unroll
    for (int j = 0; j < 4; j++) {
        int i = base + j;
        if (i <= n) offsets[i] = excl;
        if (i < n) cursor[i] = excl;
        excl += v[j];
    }
}

__global__ void fill_kernel(const int* __restrict__ esrc, const int* __restrict__ edst,
                            int* __restrict__ cursor, int* __restrict__ csr_src, int n_edges) {
    int e = blockIdx.x * 256 + threadIdx.x;
    if (e >= n_edges) return;
    int pos = atomicAdd(&cursor[edst[e]], 1);
    csr_src[pos] = esrc[e];
}

// ---------------- W prep: wt[mat][n][k] = bf16(W[mat][k][n]) ----------------
__global__ void wsplit_kernel(const float* __restrict__ Wa, const float* __restrict__ Wb,
                              short* __restrict__ wt) {
    int mat = blockIdx.y;
    const float* W = (mat & 1) ? (Wb + (size_t)(mat >> 1) * D * D)
                               : (Wa + (size_t)(mat >> 1) * D * D);
    int idx = blockIdx.x * 256 + threadIdx.x;
    int n = idx >> 7, k = idx & 127;
    wt[(size_t)mat * D * D + idx] = (short)bf16_rne(W[k * D + n]);
}

// ---------------- fused layer: H_out = relu(relu((H+agg) @ Wa + ba) @ Wb + bb) ----------------
// block: 64 nodes, 512 threads (8 waves). Node-parallel aggregation, 8 lanes/node x 32B/lane
// (4 independent 16B loads in flight per thread with 2-way edge unroll), then 2 MFMA GEMMs.
// LDS: zsh 16KB (z tile, reused for t tile) + wa 32KB + wb 32KB = 80KB -> 2 blocks/CU.
// 16B chunks XOR-swizzled: chunk c of row r at (c ^ (r&15)) -> <=2-way bank aliasing (free).
__global__ __launch_bounds__(512, 4) void layer_kernel(
        const int* __restrict__ offsets, const int* __restrict__ csr_src,
        const short* __restrict__ h_in, const short* __restrict__ wta,
        const short* __restrict__ wtb, const float* __restrict__ ba,
        const float* __restrict__ bb, short* __restrict__ h_out, int n_rows) {
    __shared__ __align__(16) short zsh[64 * 128];     // z tile, then t tile
    __shared__ __align__(16) short wa[128 * 128];
    __shared__ __align__(16) short wb[128 * 128];

    const int tid  = threadIdx.x;
    const int row0 = blockIdx.x * 64;

    // stage Wa/Wb ([n][k] bf16): 2048 chunks each, 4 iters each over 512 threads
    #pragma unroll
    for (int i = 0; i < 4; i++) {
        int g = i * 512 + tid;
        int n = g >> 4, c = g & 15;
        int off = (n * 16 + (c ^ (n & 15))) * 8;
        *reinterpret_cast<short8*>(&wa[off]) =
            *reinterpret_cast<const short8*>(wta + n * D + c * 8);
        *reinterpret_cast<short8*>(&wb[off]) =
            *reinterpret_cast<const short8*>(wtb + n * D + c * 8);
    }

    // aggregation: row r = tid>>3 (one pass over all 64 rows), lane l8 = tid&7 owns 32B
    // z[r] = h[row0+r] + sum_{j->row0+r} h[j]   (fp32 acc, bf16 out; same CSR edge order as R5)
    {
        const int r  = tid >> 3;
        const int l8 = tid & 7;
        const int gr = row0 + r;
        float acc[16];
        if (gr < n_rows) {
            const size_t cb = (size_t)gr * D + l8 * 16;
            short8 s0 = *reinterpret_cast<const short8*>(h_in + cb);
            short8 s1 = *reinterpret_cast<const short8*>(h_in + cb + 8);
            #pragma unroll
            for (int j = 0; j < 8; j++) { acc[j] = bf16_to_f32(s0[j]); acc[8 + j] = bf16_to_f32(s1[j]); }
            int beg = offsets[gr];
            int end = offsets[gr + 1];
            int e = beg;
            for (; e + 1 < end; e += 2) {
                int sA = csr_src[e];
                int sB = csr_src[e + 1];
                const short* pA = h_in + (size_t)sA * D + l8 * 16;
                const short* pB = h_in + (size_t)sB * D + l8 * 16;
                short8 a0 = *reinterpret_cast<const short8*>(pA);
                short8 a1 = *reinterpret_cast<const short8*>(pA + 8);
                short8 b0 = *reinterpret_cast<const short8*>(pB);
                short8 b1 = *reinterpret_cast<const short8*>(pB + 8);
                #pragma unroll
                for (int j = 0; j < 8; j++) {
                    acc[j]     += bf16_to_f32(a0[j]) + bf16_to_f32(b0[j]);
                    acc[8 + j] += bf16_to_f32(a1[j]) + bf16_to_f32(b1[j]);
                }
            }
            if (e < end) {
                int sA = csr_src[e];
                const short* pA = h_in + (size_t)sA * D + l8 * 16;
                short8 a0 = *reinterpret_cast<const short8*>(pA);
                short8 a1 = *reinterpret_cast<const short8*>(pA + 8);
                #pragma unroll
                for (int j = 0; j < 8; j++) {
                    acc[j]     += bf16_to_f32(a0[j]);
                    acc[8 + j] += bf16_to_f32(a1[j]);
                }
            }
        } else {
            #pragma unroll
            for (int j = 0; j < 16; j++) acc[j] = 0.f;
        }
        short8 o0, o1;
        #pragma unroll
        for (int j = 0; j < 8; j++) { o0[j] = (short)bf16_rne(acc[j]); o1[j] = (short)bf16_rne(acc[8 + j]); }
        const int c0 = 2 * l8, c1 = 2 * l8 + 1;
        *reinterpret_cast<short8*>(&zsh[(r * 16 + (c0 ^ (r & 15))) * 8]) = o0;
        *reinterpret_cast<short8*>(&zsh[(r * 16 + (c1 ^ (r & 15))) * 8]) = o1;
    }
    __syncthreads();

    const int lane = tid & 63;
    const int wave = tid >> 6;
    const int wr   = wave >> 1;     // 16-row group (0..3)
    const int wc   = wave & 1;      // 64-col group
    const int lm   = lane & 15;
    const int quad = lane >> 4;

    // ---- GEMM1: t = relu(z @ Wa + ba) ----
    floatx4 acc1[4];
    #pragma unroll
    for (int b = 0; b < 4; b++) acc1[b] = floatx4{0.f, 0.f, 0.f, 0.f};
    {
        const int r = wr * 16 + lm;
        #pragma unroll
        for (int ks = 0; ks < 4; ks++) {
            const int c = ks * 4 + quad;
            short8 av = *reinterpret_cast<const short8*>(&zsh[(r * 16 + (c ^ (r & 15))) * 8]);
            #pragma unroll
            for (int cs = 0; cs < 4; cs++) {
                int nn = wc * 64 + cs * 16 + lm;
                short8 bv = *reinterpret_cast<const short8*>(&wa[(nn * 16 + (c ^ (nn & 15))) * 8]);
                acc1[cs] = __builtin_amdgcn_mfma_f32_16x16x32_bf16(av, bv, acc1[cs], 0, 0, 0);
            }
        }
    }
    __syncthreads();   // all zsh reads complete before t overwrites it

    // epilogue1: bias + relu + bf16, write t into zsh (C layout: row=quad*4+reg, col=lm)
    #pragma unroll
    for (int cs = 0; cs < 4; cs++) {
        int col = wc * 64 + cs * 16 + lm;
        float bva = ba[col];
        int cj = col >> 3, ci = col & 7;
        #pragma unroll
        for (int reg = 0; reg < 4; reg++) {
            int r = wr * 16 + quad * 4 + reg;
            float v = fmaxf(acc1[cs][reg] + bva, 0.f);
            zsh[(r * 16 + (cj ^ (r & 15))) * 8 + ci] = (short)bf16_rne(v);
        }
    }
    __syncthreads();

    // ---- GEMM2: h = relu(t @ Wb + bb) ----
    floatx4 acc2[4];
    #pragma unroll
    for (int b = 0; b < 4; b++) acc2[b] = floatx4{0.f, 0.f, 0.f, 0.f};
    {
        const int r = wr * 16 + lm;
        #pragma unroll
        for (int ks = 0; ks < 4; ks++) {
            const int c = ks * 4 + quad;
            short8 av = *reinterpret_cast<const short8*>(&zsh[(r * 16 + (c ^ (r & 15))) * 8]);
            #pragma unroll
            for (int cs = 0; cs < 4; cs++) {
                int nn = wc * 64 + cs * 16 + lm;
                short8 bv = *reinterpret_cast<const short8*>(&wb[(nn * 16 + (c ^ (nn & 15))) * 8]);
                acc2[cs] = __builtin_amdgcn_mfma_f32_16x16x32_bf16(av, bv, acc2[cs], 0, 0, 0);
            }
        }
    }

    // epilogue2: bias + relu + bf16 -> global
    #pragma unroll
    for (int cs = 0; cs < 4; cs++) {
        int col = wc * 64 + cs * 16 + lm;
        float bvb = bb[col];
        #pragma unroll
        for (int reg = 0; reg < 4; reg++) {
            int r = row0 + wr * 16 + quad * 4 + reg;
            if (r < n_rows) {
                float v = fmaxf(acc2[cs][reg] + bvb, 0.f);
                h_out[(size_t)r * D + col] = (short)bf16_rne(v);
            }
        }
    }
}

// ---------------- pooling: pooled[c] = sum_r f32(H[r][c]) ----------------
__global__ void zero_kernel(float* __restrict__ p) { p[threadIdx.x] = 0.f; }

__global__ void pool_kernel(const short* __restrict__ h, float* __restrict__ pooled, int n_rows) {
    const int c8 = threadIdx.x & 15;
    const int rg = threadIdx.x >> 4;
    const int r0 = blockIdx.x * 256;
    const int rend = min(r0 + 256, n_rows);
    float acc[8];
    #pragma unroll
    for (int j = 0; j < 8; j++) acc[j] = 0.f;
    for (int r = r0 + rg; r < rend; r += 16) {
        short8 v = *reinterpret_cast<const short8*>(h + (size_t)r * D + c8 * 8);
        #pragma unroll
        for (int j = 0; j < 8; j++) acc[j] += bf16_to_f32(v[j]);
    }
    __shared__ float red[16][128];
    #pragma unroll
    for (int j = 0; j < 8; j++) red[rg][c8 * 8 + j] = acc[j];
    __syncthreads();
    if (threadIdx.x < 128) {
        float s = 0.f;
        #pragma unroll
        for (int g = 0; g < 16; g++) s += red[g][threadIdx.x];
        atomicAdd(&pooled[threadIdx.x], s);
    }
}

// ---------------- final linear (fp32 exact) ----------------
__global__ void final_kernel(const float* __restrict__ pooled, const float* __restrict__ Wlin,
                             const float* __restrict__ blin, float* __restrict__ out) {
    const int j = threadIdx.x;
    __shared__ float p[D];
    p[j] = pooled[j];
    __syncthreads();
    float s = blin[j];
    #pragma unroll 8
    for (int k = 0; k < D; k++) s += p[k] * Wlin[k * D + j];
    out[j] = s;
}

extern "C" void kernel_launch(void* const* d_in, const int* in_sizes, int n_in,
                              void* d_out, int out_size, void* d_ws, size_t ws_size,
                              hipStream_t stream) {
    const int*   x    = (const int*)d_in[0];
    const int*   ei   = (const int*)d_in[1];
    const float* emb  = (const float*)d_in[2];
    const float* Wa   = (const float*)d_in[3];
    const float* ba   = (const float*)d_in[4];
    const float* Wb   = (const float*)d_in[5];
    const float* bb   = (const float*)d_in[6];
    const float* Wlin = (const float*)d_in[7];
    const float* blin = (const float*)d_in[8];
    float* out = (float*)d_out;

    const int N = in_sizes[0];
    const int E = in_sizes[1] / 2;
    const int* esrc = ei;
    const int* edst = ei + E;

    // workspace layout: H (bf16, double-buffered) | pooled | CSR | wt
    short* H0 = (short*)d_ws;                       // N*D
    short* H1 = H0 + (size_t)N * D;                 // N*D
    float* pooled = (float*)(H1 + (size_t)N * D);   // 128
    int* deg     = (int*)(pooled + 128);            // N
    int* offsets = deg + N;                         // N+1
    int* cursor  = offsets + (N + 1);               // N
    int* bsums   = cursor + N;                      // 4096
    int* csr_src = bsums + 4096;                    // E
    uintptr_t wt_addr = ((uintptr_t)(csr_src + E) + 15) & ~(uintptr_t)15;
    short* wt = (short*)wt_addr;                    // [10][128][128] bf16

    const int scan_blocks = (N + 1 + SCAN_TILE - 1) / SCAN_TILE;

    wsplit_kernel<<<dim3(64, 2 * NLAYERS), 256, 0, stream>>>(Wa, Wb, wt);

    zero_int_kernel<<<(N + 255) / 256, 256, 0, stream>>>(deg, N);
    hist_kernel<<<(E + 255) / 256, 256, 0, stream>>>(edst, deg, E);
    scan_sums_kernel<<<scan_blocks, 256, 0, stream>>>(deg, bsums, N);
    scan_bsums_kernel<<<1, 256, 0, stream>>>(bsums, scan_blocks);
    scan_final_kernel<<<scan_blocks, 256, 0, stream>>>(deg, bsums, offsets, cursor, N);
    fill_kernel<<<(E + 255) / 256, 256, 0, stream>>>(esrc, edst, cursor, csr_src, E);

    gather_kernel<<<(N * 32 + 255) / 256, 256, 0, stream>>>(x, emb, H0, N);

    const int layer_blocks = (N + 63) / 64;
    short* hin = H0; short* hout = H1;
    for (int l = 0; l < NLAYERS; l++) {
        layer_kernel<<<layer_blocks, 512, 0, stream>>>(
            offsets, csr_src, hin,
            wt + (size_t)(2 * l) * D * D, wt + (size_t)(2 * l + 1) * D * D,
            ba + (size_t)l * D, bb + (size_t)l * D, hout, N);
        short* tmp = hin; hin = hout; hout = tmp;
    }

    zero_kernel<<<1, 128, 0, stream>>>(pooled);
    pool_kernel<<<(N + 255) / 256, 256, 0, stream>>>(hin, pooled, N);
    final_kernel<<<1, 128, 0, stream>>>(pooled, Wlin, blin, out);
}

// Round 8
// 453.281 us; speedup vs baseline: 6.2779x; 1.0140x over previous
//
#include <hip/hip_runtime.h>

#define D 128
#define NLAYERS 5
#define SCAN_TILE 1024

using short8  = __attribute__((ext_vector_type(8))) short;
using short4v = __attribute__((ext_vector_type(4))) short;
using floatx4 = __attribute__((ext_vector_type(4))) float;

__device__ __forceinline__ unsigned bf16_rne(float x) {
    unsigned u = __float_as_uint(x);
    return (u + 0x7fffu + ((u >> 16) & 1u)) >> 16;
}
__device__ __forceinline__ float bf16_to_f32(short s) {
    return __uint_as_float(((unsigned)(unsigned short)s) << 16);
}

// ---------------- gather: H = bf16(emb[x]) ----------------
__global__ void gather_kernel(const int* __restrict__ x, const float* __restrict__ emb,
                              short* __restrict__ h, int n_nodes) {
    int tid = blockIdx.x * 256 + threadIdx.x;
    int node = tid >> 5;
    if (node >= n_nodes) return;
    int lane = tid & 31;
    int s = x[node];
    const float4 v = *reinterpret_cast<const float4*>(emb + (size_t)s * D + lane * 4);
    short4v o;
    o[0] = (short)bf16_rne(v.x); o[1] = (short)bf16_rne(v.y);
    o[2] = (short)bf16_rne(v.z); o[3] = (short)bf16_rne(v.w);
    *reinterpret_cast<short4v*>(h + (size_t)node * D + lane * 4) = o;
}

// ---------------- CSR build ----------------
__global__ void zero_int_kernel(int* __restrict__ p, int n) {
    int i = blockIdx.x * 256 + threadIdx.x;
    if (i < n) p[i] = 0;
}

__global__ void hist_kernel(const int* __restrict__ edst, int* __restrict__ deg, int n_edges) {
    int e = blockIdx.x * 256 + threadIdx.x;
    if (e < n_edges) atomicAdd(&deg[edst[e]], 1);
}

__global__ void scan_sums_kernel(const int* __restrict__ deg, int* __restrict__ bsums, int n) {
    __shared__ int red[256];
    int base = blockIdx.x * SCAN_TILE + threadIdx.x * 4;
    int s = 0;
    #pragma unroll
    for (int j = 0; j < 4; j++) {
        int i = base + j;
        if (i < n) s += deg[i];
    }
    red[threadIdx.x] = s;
    __syncthreads();
    for (int off = 128; off > 0; off >>= 1) {
        if (threadIdx.x < off) red[threadIdx.x] += red[threadIdx.x + off];
        __syncthreads();
    }
    if (threadIdx.x == 0) bsums[blockIdx.x] = red[0];
}

__global__ void scan_bsums_kernel(int* __restrict__ bsums, int nblocks) {
    __shared__ int sdata[256];
    int carry = 0;
    for (int base = 0; base < nblocks; base += 256) {
        int i = base + threadIdx.x;
        int v = (i < nblocks) ? bsums[i] : 0;
        sdata[threadIdx.x] = v;
        __syncthreads();
        for (int off = 1; off < 256; off <<= 1) {
            int t = (threadIdx.x >= off) ? sdata[threadIdx.x - off] : 0;
            __syncthreads();
            sdata[threadIdx.x] += t;
            __syncthreads();
        }
        int incl = sdata[threadIdx.x];
        if (i < nblocks) bsums[i] = carry + incl - v;
        carry += sdata[255];
        __syncthreads();
    }
}

__global__ void scan_final_kernel(const int* __restrict__ deg, const int* __restrict__ bsums,
                                  int* __restrict__ offsets, int* __restrict__ cursor, int n) {
    __shared__ int sdata[256];
    int base = blockIdx.x * SCAN_TILE + threadIdx.x * 4;
    int v[4];
    int s = 0;
    #pragma unroll
    for (int j = 0; j < 4; j++) {
        int i = base + j;
        v[j] = (i < n) ? deg[i] : 0;
        s += v[j];
    }
    sdata[threadIdx.x] = s;
    __syncthreads();
    for (int off = 1; off < 256; off <<= 1) {
        int t = (threadIdx.x >= off) ? sdata[threadIdx.x - off] : 0;
        __syncthreads();
        sdata[threadIdx.x] += t;
        __syncthreads();
    }
    int excl = sdata[threadIdx.x] - s + bsums[blockIdx.x];
    #pragma unroll
    for (int j = 0; j < 4; j++) {
        int i = base + j;
        if (i <= n) offsets[i] = excl;
        if (i < n) cursor[i] = excl;
        excl += v[j];
    }
}

__global__ void fill_kernel(const int* __restrict__ esrc, const int* __restrict__ edst,
                            int* __restrict__ cursor, int* __restrict__ csr_src, int n_edges) {
    int e = blockIdx.x * 256 + threadIdx.x;
    if (e >= n_edges) return;
    int pos = atomicAdd(&cursor[edst[e]], 1);
    csr_src[pos] = esrc[e];
}

// ---------------- W prep: wt[mat][n][k] = bf16(W[mat][k][n]) ----------------
__global__ void wsplit_kernel(const float* __restrict__ Wa, const float* __restrict__ Wb,
                              short* __restrict__ wt) {
    int mat = blockIdx.y;
    const float* W = (mat & 1) ? (Wb + (size_t)(mat >> 1) * D * D)
                               : (Wa + (size_t)(mat >> 1) * D * D);
    int idx = blockIdx.x * 256 + threadIdx.x;
    int n = idx >> 7, k = idx & 127;
    wt[(size_t)mat * D * D + idx] = (short)bf16_rne(W[k * D + n]);
}

// ---------------- fused layer: H_out = relu(relu((H+agg) @ Wa + ba) @ Wb + bb) ----------------
// block: 64 nodes, 512 threads (8 waves). Node-parallel aggregation, 8 lanes/node x 32B/lane,
// 4-way edge unroll -> 8 independent 16B loads in flight per thread. Then 2 MFMA GEMMs.
// LDS: zsh 16KB (z tile, reused for t tile) + wa 32KB + wb 32KB = 80KB -> 2 blocks/CU.
// 16B chunks XOR-swizzled: chunk c of row r at (c ^ (r&15)) -> <=2-way bank aliasing (free).
__global__ __launch_bounds__(512, 4) void layer_kernel(
        const int* __restrict__ offsets, const int* __restrict__ csr_src,
        const short* __restrict__ h_in, const short* __restrict__ wta,
        const short* __restrict__ wtb, const float* __restrict__ ba,
        const float* __restrict__ bb, short* __restrict__ h_out, int n_rows) {
    __shared__ __align__(16) short zsh[64 * 128];     // z tile, then t tile
    __shared__ __align__(16) short wa[128 * 128];
    __shared__ __align__(16) short wb[128 * 128];

    const int tid  = threadIdx.x;
    const int row0 = blockIdx.x * 64;

    // stage Wa/Wb ([n][k] bf16): 2048 chunks each, 4 iters each over 512 threads
    #pragma unroll
    for (int i = 0; i < 4; i++) {
        int g = i * 512 + tid;
        int n = g >> 4, c = g & 15;
        int off = (n * 16 + (c ^ (n & 15))) * 8;
        *reinterpret_cast<short8*>(&wa[off]) =
            *reinterpret_cast<const short8*>(wta + n * D + c * 8);
        *reinterpret_cast<short8*>(&wb[off]) =
            *reinterpret_cast<const short8*>(wtb + n * D + c * 8);
    }

    // aggregation: row r = tid>>3, lane l8 = tid&7 owns 32B. 4-way edge unroll:
    // 8 independent 16B loads in flight per thread per round.
    {
        const int r  = tid >> 3;
        const int l8 = tid & 7;
        const int gr = row0 + r;
        float acc[16];
        if (gr < n_rows) {
            const size_t cb = (size_t)gr * D + l8 * 16;
            short8 s0 = *reinterpret_cast<const short8*>(h_in + cb);
            short8 s1 = *reinterpret_cast<const short8*>(h_in + cb + 8);
            #pragma unroll
            for (int j = 0; j < 8; j++) { acc[j] = bf16_to_f32(s0[j]); acc[8 + j] = bf16_to_f32(s1[j]); }
            int beg = offsets[gr];
            int end = offsets[gr + 1];
            int e = beg;
            for (; e + 3 < end; e += 4) {
                int sA = csr_src[e];
                int sB = csr_src[e + 1];
                int sC = csr_src[e + 2];
                int sD = csr_src[e + 3];
                const short* pA = h_in + (size_t)sA * D + l8 * 16;
                const short* pB = h_in + (size_t)sB * D + l8 * 16;
                const short* pC = h_in + (size_t)sC * D + l8 * 16;
                const short* pD = h_in + (size_t)sD * D + l8 * 16;
                short8 a0 = *reinterpret_cast<const short8*>(pA);
                short8 a1 = *reinterpret_cast<const short8*>(pA + 8);
                short8 b0 = *reinterpret_cast<const short8*>(pB);
                short8 b1 = *reinterpret_cast<const short8*>(pB + 8);
                short8 c0 = *reinterpret_cast<const short8*>(pC);
                short8 c1 = *reinterpret_cast<const short8*>(pC + 8);
                short8 d0 = *reinterpret_cast<const short8*>(pD);
                short8 d1 = *reinterpret_cast<const short8*>(pD + 8);
                #pragma unroll
                for (int j = 0; j < 8; j++) {
                    acc[j]     += (bf16_to_f32(a0[j]) + bf16_to_f32(b0[j]))
                                + (bf16_to_f32(c0[j]) + bf16_to_f32(d0[j]));
                    acc[8 + j] += (bf16_to_f32(a1[j]) + bf16_to_f32(b1[j]))
                                + (bf16_to_f32(c1[j]) + bf16_to_f32(d1[j]));
                }
            }
            for (; e < end; e++) {
                int sA = csr_src[e];
                const short* pA = h_in + (size_t)sA * D + l8 * 16;
                short8 a0 = *reinterpret_cast<const short8*>(pA);
                short8 a1 = *reinterpret_cast<const short8*>(pA + 8);
                #pragma unroll
                for (int j = 0; j < 8; j++) {
                    acc[j]     += bf16_to_f32(a0[j]);
                    acc[8 + j] += bf16_to_f32(a1[j]);
                }
            }
        } else {
            #pragma unroll
            for (int j = 0; j < 16; j++) acc[j] = 0.f;
        }
        short8 o0, o1;
        #pragma unroll
        for (int j = 0; j < 8; j++) { o0[j] = (short)bf16_rne(acc[j]); o1[j] = (short)bf16_rne(acc[8 + j]); }
        const int c0i = 2 * l8, c1i = 2 * l8 + 1;
        *reinterpret_cast<short8*>(&zsh[(r * 16 + (c0i ^ (r & 15))) * 8]) = o0;
        *reinterpret_cast<short8*>(&zsh[(r * 16 + (c1i ^ (r & 15))) * 8]) = o1;
    }
    __syncthreads();

    const int lane = tid & 63;
    const int wave = tid >> 6;
    const int wr   = wave >> 1;     // 16-row group (0..3)
    const int wc   = wave & 1;      // 64-col group
    const int lm   = lane & 15;
    const int quad = lane >> 4;

    // ---- GEMM1: t = relu(z @ Wa + ba) ----
    floatx4 acc1[4];
    #pragma unroll
    for (int b = 0; b < 4; b++) acc1[b] = floatx4{0.f, 0.f, 0.f, 0.f};
    {
        const int r = wr * 16 + lm;
        #pragma unroll
        for (int ks = 0; ks < 4; ks++) {
            const int c = ks * 4 + quad;
            short8 av = *reinterpret_cast<const short8*>(&zsh[(r * 16 + (c ^ (r & 15))) * 8]);
            #pragma unroll
            for (int cs = 0; cs < 4; cs++) {
                int nn = wc * 64 + cs * 16 + lm;
                short8 bv = *reinterpret_cast<const short8*>(&wa[(nn * 16 + (c ^ (nn & 15))) * 8]);
                acc1[cs] = __builtin_amdgcn_mfma_f32_16x16x32_bf16(av, bv, acc1[cs], 0, 0, 0);
            }
        }
    }
    __syncthreads();   // all zsh reads complete before t overwrites it

    // epilogue1: bias + relu + bf16, write t into zsh (C layout: row=quad*4+reg, col=lm)
    #pragma unroll
    for (int cs = 0; cs < 4; cs++) {
        int col = wc * 64 + cs * 16 + lm;
        float bva = ba[col];
        int cj = col >> 3, ci = col & 7;
        #pragma unroll
        for (int reg = 0; reg < 4; reg++) {
            int r = wr * 16 + quad * 4 + reg;
            float v = fmaxf(acc1[cs][reg] + bva, 0.f);
            zsh[(r * 16 + (cj ^ (r & 15))) * 8 + ci] = (short)bf16_rne(v);
        }
    }
    __syncthreads();

    // ---- GEMM2: h = relu(t @ Wb + bb) ----
    floatx4 acc2[4];
    #pragma unroll
    for (int b = 0; b < 4; b++) acc2[b] = floatx4{0.f, 0.f, 0.f, 0.f};
    {
        const int r = wr * 16 + lm;
        #pragma unroll
        for (int ks = 0; ks < 4; ks++) {
            const int c = ks * 4 + quad;
            short8 av = *reinterpret_cast<const short8*>(&zsh[(r * 16 + (c ^ (r & 15))) * 8]);
            #pragma unroll
            for (int cs = 0; cs < 4; cs++) {
                int nn = wc * 64 + cs * 16 + lm;
                short8 bv = *reinterpret_cast<const short8*>(&wb[(nn * 16 + (c ^ (nn & 15))) * 8]);
                acc2[cs] = __builtin_amdgcn_mfma_f32_16x16x32_bf16(av, bv, acc2[cs], 0, 0, 0);
            }
        }
    }

    // epilogue2: bias + relu + bf16 -> global
    #pragma unroll
    for (int cs = 0; cs < 4; cs++) {
        int col = wc * 64 + cs * 16 + lm;
        float bvb = bb[col];
        #pragma unroll
        for (int reg = 0; reg < 4; reg++) {
            int r = row0 + wr * 16 + quad * 4 + reg;
            if (r < n_rows) {
                float v = fmaxf(acc2[cs][reg] + bvb, 0.f);
                h_out[(size_t)r * D + col] = (short)bf16_rne(v);
            }
        }
    }
}

// ---------------- pooling: pooled[c] = sum_r f32(H[r][c]) ----------------
__global__ void zero_kernel(float* __restrict__ p) { p[threadIdx.x] = 0.f; }

__global__ void pool_kernel(const short* __restrict__ h, float* __restrict__ pooled, int n_rows) {
    const int c8 = threadIdx.x & 15;
    const int rg = threadIdx.x >> 4;
    const int r0 = blockIdx.x * 256;
    const int rend = min(r0 + 256, n_rows);
    float acc[8];
    #pragma unroll
    for (int j = 0; j < 8; j++) acc[j] = 0.f;
    for (int r = r0 + rg; r < rend; r += 16) {
        short8 v = *reinterpret_cast<const short8*>(h + (size_t)r * D + c8 * 8);
        #pragma unroll
        for (int j = 0; j < 8; j++) acc[j] += bf16_to_f32(v[j]);
    }
    __shared__ float red[16][128];
    #pragma unroll
    for (int j = 0; j < 8; j++) red[rg][c8 * 8 + j] = acc[j];
    __syncthreads();
    if (threadIdx.x < 128) {
        float s = 0.f;
        #pragma unroll
        for (int g = 0; g < 16; g++) s += red[g][threadIdx.x];
        atomicAdd(&pooled[threadIdx.x], s);
    }
}

// ---------------- final linear (fp32 exact) ----------------
__global__ void final_kernel(const float* __restrict__ pooled, const float* __restrict__ Wlin,
                             const float* __restrict__ blin, float* __restrict__ out) {
    const int j = threadIdx.x;
    __shared__ float p[D];
    p[j] = pooled[j];
    __syncthreads();
    float s = blin[j];
    #pragma unroll 8
    for (int k = 0; k < D; k++) s += p[k] * Wlin[k * D + j];
    out[j] = s;
}

extern "C" void kernel_launch(void* const* d_in, const int* in_sizes, int n_in,
                              void* d_out, int out_size, void* d_ws, size_t ws_size,
                              hipStream_t stream) {
    const int*   x    = (const int*)d_in[0];
    const int*   ei   = (const int*)d_in[1];
    const float* emb  = (const float*)d_in[2];
    const float* Wa   = (const float*)d_in[3];
    const float* ba   = (const float*)d_in[4];
    const float* Wb   = (const float*)d_in[5];
    const float* bb   = (const float*)d_in[6];
    const float* Wlin = (const float*)d_in[7];
    const float* blin = (const float*)d_in[8];
    float* out = (float*)d_out;

    const int N = in_sizes[0];
    const int E = in_sizes[1] / 2;
    const int* esrc = ei;
    const int* edst = ei + E;

    // workspace layout: H (bf16, double-buffered) | pooled | CSR | wt
    short* H0 = (short*)d_ws;                       // N*D
    short* H1 = H0 + (size_t)N * D;                 // N*D
    float* pooled = (float*)(H1 + (size_t)N * D);   // 128
    int* deg     = (int*)(pooled + 128);            // N
    int* offsets = deg + N;                         // N+1
    int* cursor  = offsets + (N + 1);               // N
    int* bsums   = cursor + N;                      // 4096
    int* csr_src = bsums + 4096;                    // E
    uintptr_t wt_addr = ((uintptr_t)(csr_src + E) + 15) & ~(uintptr_t)15;
    short* wt = (short*)wt_addr;                    // [10][128][128] bf16

    const int scan_blocks = (N + 1 + SCAN_TILE - 1) / SCAN_TILE;

    wsplit_kernel<<<dim3(64, 2 * NLAYERS), 256, 0, stream>>>(Wa, Wb, wt);

    zero_int_kernel<<<(N + 255) / 256, 256, 0, stream>>>(deg, N);
    hist_kernel<<<(E + 255) / 256, 256, 0, stream>>>(edst, deg, E);
    scan_sums_kernel<<<scan_blocks, 256, 0, stream>>>(deg, bsums, N);
    scan_bsums_kernel<<<1, 256, 0, stream>>>(bsums, scan_blocks);
    scan_final_kernel<<<scan_blocks, 256, 0, stream>>>(deg, bsums, offsets, cursor, N);
    fill_kernel<<<(E + 255) / 256, 256, 0, stream>>>(esrc, edst, cursor, csr_src, E);

    gather_kernel<<<(N * 32 + 255) / 256, 256, 0, stream>>>(x, emb, H0, N);

    const int layer_blocks = (N + 63) / 64;
    short* hin = H0; short* hout = H1;
    for (int l = 0; l < NLAYERS; l++) {
        layer_kernel<<<layer_blocks, 512, 0, stream>>>(
            offsets, csr_src, hin,
            wt + (size_t)(2 * l) * D * D, wt + (size_t)(2 * l + 1) * D * D,
            ba + (size_t)l * D, bb + (size_t)l * D, hout, N);
        short* tmp = hin; hin = hout; hout = tmp;
    }

    zero_kernel<<<1, 128, 0, stream>>>(pooled);
    pool_kernel<<<(N + 255) / 256, 256, 0, stream>>>(hin, pooled, N);
    final_kernel<<<1, 128, 0, stream>>>(pooled, Wlin, blin, out);
}